// Round 4
// baseline (482.309 us; speedup 1.0000x reference)
//
#include <hip/hip_runtime.h>
#include <math.h>

#define HIDDEN 256
#define NUM_CLASSES 53
#define CHUNK 64   // rows per K1 block

// ws layout: repre_un[n_bags*512] f32 | s[2*n_bags] f32 | seg[n_rows] i32

// ---------------- K0: zero accumulators + seg fill (block per bag) ----------
__global__ __launch_bounds__(256) void k0_init(
    const int* __restrict__ scope, int* __restrict__ seg,
    float* __restrict__ repre, float* __restrict__ s)
{
    const int b = blockIdx.x;
    const int t = threadIdx.x;
    repre[(size_t)b * 512 + t]       = 0.f;
    repre[(size_t)b * 512 + 256 + t] = 0.f;
    if (t < 2) s[2 * b + t] = 0.f;
    const int st = scope[b], en = scope[b + 1];
    for (int i = st + t; i < en; i += 256) seg[i] = b;
}

// ---------------- K1: single balanced pass over x ---------------------------
__global__ __launch_bounds__(256) void k1_main(
    const float* __restrict__ x,
    const float* __restrict__ rel_emb0,
    const float* __restrict__ rel_emb1,
    const int* __restrict__ relation_levels,
    const int* __restrict__ label_index,
    const int* __restrict__ seg,
    float* __restrict__ repre,
    float* __restrict__ s)
{
    const int c0   = blockIdx.x * CHUNK;
    const int tid  = threadIdx.x;
    const int lane = tid & 63;
    const int wave = tid >> 6;
    const int half = lane >> 5;
    const int j    = lane & 31;
    const int colb = j * 8;
    const int stream = wave * 2 + half;   // 0..7, row = c0 + 8k + stream

    __shared__ float e_lds[CHUNK][2];
    __shared__ int   s_seg[CHUNK];

    if (tid < CHUNK) s_seg[tid] = seg[c0 + tid];

    // ---- phase 1: logits -> e into LDS (8 parallel row streams) ----
    #pragma unroll
    for (int k = 0; k < CHUNK / 8; ++k) {
        const int row = c0 + 8 * k + stream;
        const float* xp = x + (size_t)row * HIDDEN + colb;
        const float4 xa = *reinterpret_cast<const float4*>(xp);
        const float4 xb = *reinterpret_cast<const float4*>(xp + 4);
        const int lbl = label_index[row];   // uniform within half -> broadcast
        const int2 rl = *reinterpret_cast<const int2*>(relation_levels + 2 * lbl);
        const float* p0 = rel_emb0 + (size_t)rl.x * HIDDEN + colb;
        const float* p1 = rel_emb1 + (size_t)rl.y * HIDDEN + colb;
        const float4 r0a = *reinterpret_cast<const float4*>(p0);
        const float4 r0b = *reinterpret_cast<const float4*>(p0 + 4);
        const float4 r1a = *reinterpret_cast<const float4*>(p1);
        const float4 r1b = *reinterpret_cast<const float4*>(p1 + 4);

        float lg0 = xa.x*r0a.x + xa.y*r0a.y + xa.z*r0a.z + xa.w*r0a.w
                  + xb.x*r0b.x + xb.y*r0b.y + xb.z*r0b.z + xb.w*r0b.w;
        float lg1 = xa.x*r1a.x + xa.y*r1a.y + xa.z*r1a.z + xa.w*r1a.w
                  + xb.x*r1b.x + xb.y*r1b.y + xb.z*r1b.z + xb.w*r1b.w;

        #pragma unroll
        for (int off = 16; off > 0; off >>= 1) {   // 32-lane reduce, stays in half
            lg0 += __shfl_xor(lg0, off, 64);
            lg1 += __shfl_xor(lg1, off, 64);
        }
        if (j == 0) {
            e_lds[8 * k + stream][0] = __expf(lg0);
            e_lds[8 * k + stream][1] = __expf(lg1);
        }
    }
    __syncthreads();

    // ---- phase 2: thread-per-column accumulation in bag order ----
    // thread t owns hidden column t (both levels); rows are bag-sorted.
    float acc0 = 0.f, acc1 = 0.f, se0 = 0.f, se1 = 0.f;
    int curbag = s_seg[0];
    for (int r = 0; r < CHUNK; ++r) {
        const float e0 = e_lds[r][0];     // broadcast reads
        const float e1 = e_lds[r][1];
        const float xv = x[(size_t)(c0 + r) * HIDDEN + tid];  // L1/L2 hit
        acc0 += e0 * xv;
        acc1 += e1 * xv;
        se0  += e0;
        se1  += e1;
        const bool last = (r == CHUNK - 1);
        if (last || s_seg[r + 1] != curbag) {   // wave-uniform branch
            atomicAdd(&repre[(size_t)curbag * 512 + tid],       acc0);
            atomicAdd(&repre[(size_t)curbag * 512 + 256 + tid], acc1);
            if (tid == 0) atomicAdd(&s[2 * curbag],     se0);
            if (tid == 1) atomicAdd(&s[2 * curbag + 1], se1);
            acc0 = acc1 = se0 = se1 = 0.f;
            if (!last) curbag = s_seg[r + 1];
        }
    }
}

// ---------------- K2: normalize + head (wave per bag) -----------------------
__global__ __launch_bounds__(256) void k2_head(
    const float* __restrict__ repre,
    const float* __restrict__ s,
    const float* __restrict__ disc,
    const float* __restrict__ bias,
    float* __restrict__ out)
{
    const int tid  = threadIdx.x;
    const int lane = tid & 63;
    const int wave = tid >> 6;
    const int bag  = blockIdx.x * 4 + wave;

    __shared__ float s_rep[4][2 * HIDDEN];   // 8 KB

    const float s0 = s[2 * bag], s1 = s[2 * bag + 1];
    const float inv0 = (s0 > 0.f) ? 1.f / s0 : 0.f;
    const float inv1 = (s1 > 0.f) ? 1.f / s1 : 0.f;
    const float inv  = (lane < 32) ? inv0 : inv1;   // lane owns cols [8L,8L+8)

    const float4* rp = reinterpret_cast<const float4*>(repre + (size_t)bag * 512 + lane * 8);
    float4 v0 = rp[0], v1 = rp[1];
    v0.x *= inv; v0.y *= inv; v0.z *= inv; v0.w *= inv;
    v1.x *= inv; v1.y *= inv; v1.z *= inv; v1.w *= inv;
    float4* dst = reinterpret_cast<float4*>(&s_rep[wave][lane * 8]);
    dst[0] = v0; dst[1] = v1;
    // same-wave LDS write->read: in-order within wave, compiler inserts lgkmcnt

    if (lane < NUM_CLASSES) {
        const float4* dr = reinterpret_cast<const float4*>(disc + (size_t)lane * 512);
        const float4* rr = reinterpret_cast<const float4*>(s_rep[wave]);
        float p = 0.f;
        #pragma unroll 8
        for (int k = 0; k < 128; ++k) {
            const float4 d = dr[k];
            const float4 r = rr[k];     // same addr all lanes -> broadcast
            p += d.x * r.x + d.y * r.y + d.z * r.z + d.w * r.w;
        }
        out[bag * NUM_CLASSES + lane] = p + bias[lane];
    }
}

extern "C" void kernel_launch(void* const* d_in, const int* in_sizes, int n_in,
                              void* d_out, int out_size, void* d_ws, size_t ws_size,
                              hipStream_t stream) {
    const float* x               = (const float*)d_in[0];
    const float* rel_emb0        = (const float*)d_in[1];
    const float* rel_emb1        = (const float*)d_in[2];
    const float* disc            = (const float*)d_in[3];
    const float* bias            = (const float*)d_in[4];
    const int*   relation_levels = (const int*)d_in[5];
    const int*   label_index     = (const int*)d_in[6];
    const int*   scope           = (const int*)d_in[7];
    float*       out             = (float*)d_out;

    const int n_bags = in_sizes[7] - 1;      // 4096
    const int n_rows = in_sizes[6];          // 262144

    float* repre = (float*)d_ws;                         // n_bags*512
    float* s_ws  = repre + (size_t)n_bags * 512;         // 2*n_bags
    int*   seg   = (int*)(s_ws + 2 * n_bags);            // n_rows

    k0_init<<<n_bags, 256, 0, stream>>>(scope, seg, repre, s_ws);
    k1_main<<<n_rows / CHUNK, 256, 0, stream>>>(
        x, rel_emb0, rel_emb1, relation_levels, label_index, seg, repre, s_ws);
    k2_head<<<n_bags / 4, 256, 0, stream>>>(repre, s_ws, disc, bias, out);
}